// Round 2
// baseline (334.787 us; speedup 1.0000x reference)
//
#include <hip/hip_runtime.h>
#include <cfloat>
#include <climits>

// Retriever: cosine-sim top-5 over 100k knowledge vectors + gather.
// Strategy: bf16-MFMA screening (reads ke f32 exactly once, converts in-reg)
// -> top-16 candidates per query -> exact f32 rescore -> top-5 -> gather.

#define BQ 64
#define DD 768
#define NK 100000
#define LK 32
#define K_TOP 5
#define BN 128                      // n rows per block (phase 1)
#define WN 32                       // n rows per wave
#define NB1 ((NK + BN - 1) / BN)    // 782
#define M_PART 8                    // per-block top-M partials
#define T_CAND 16                   // rescore candidate count

typedef __attribute__((ext_vector_type(8))) short short8;
typedef __attribute__((ext_vector_type(4))) float f32x4;

// ---------- phase 0: query -> bf16 (trunc) + exact f32 norms ----------
__global__ __launch_bounds__(256) void prep_kernel(const float* __restrict__ q,
                                                   ushort* __restrict__ qbf,
                                                   float* __restrict__ qn) {
    int b = blockIdx.x, t = threadIdx.x;
    float s = 0.f;
    for (int k = t; k < DD; k += 256) {
        float v = q[b * DD + k];
        s += v * v;
        qbf[b * DD + k] = (ushort)(__float_as_uint(v) >> 16);
    }
    for (int off = 32; off > 0; off >>= 1) s += __shfl_down(s, off, 64);
    __shared__ float red[4];
    if ((t & 63) == 0) red[t >> 6] = s;
    __syncthreads();
    if (t == 0) qn[b] = sqrtf(red[0] + red[1] + red[2] + red[3]);
}

// ---------- phase 1: bf16 MFMA screening, per-block top-8 per query ----------
// Block: 256 thr = 4 waves; block tile 64q x 128n; wave tile 64q x 32n.
// No LDS staging: A(q,bf16) and B(ke,f32->bf16) fragments loaded straight
// from global per lane (contiguous 16/32B per lane), K-step 32, 24 steps.
__global__ __launch_bounds__(256) void sims_kernel(const ushort* __restrict__ qbf,
                                                   const float* __restrict__ ke,
                                                   float* __restrict__ pv,
                                                   int* __restrict__ pi) {
    __shared__ float S[BQ][BN + 2];

    const int t = threadIdx.x;
    const int w = t >> 6, l = t & 63;
    const int lg = l >> 4, li = l & 15;
    const int n0 = blockIdx.x * BN;
    const int nw = n0 + w * WN;

    // per-lane source pointers
    const ushort* aptr[4];
#pragma unroll
    for (int m = 0; m < 4; ++m) aptr[m] = qbf + (m * 16 + li) * DD + lg * 8;
    const float* bptr[2];
#pragma unroll
    for (int nf = 0; nf < 2; ++nf) {
        int r = nw + nf * 16 + li;
        if (r >= NK) r = NK - 1;               // clamp; excluded at scan
        bptr[nf] = ke + (size_t)r * DD + lg * 8;
    }

    f32x4 acc[4][2];
#pragma unroll
    for (int m = 0; m < 4; ++m)
#pragma unroll
        for (int nf = 0; nf < 2; ++nf) acc[m][nf] = (f32x4){0.f, 0.f, 0.f, 0.f};
    float bsq[2] = {0.f, 0.f};

    short8 a[2][4];
    f32x4 bf[2][2][2];

    // prologue: load k-tile 0
#pragma unroll
    for (int m = 0; m < 4; ++m) a[0][m] = *(const short8*)(aptr[m]);
#pragma unroll
    for (int nf = 0; nf < 2; ++nf)
#pragma unroll
        for (int h = 0; h < 2; ++h) bf[0][nf][h] = *(const f32x4*)(bptr[nf] + h * 4);

#pragma unroll
    for (int kt = 0; kt < 24; ++kt) {
        const int cur = kt & 1, nxt = cur ^ 1;
        if (kt < 23) {
            const int ko = (kt + 1) * 32;
#pragma unroll
            for (int m = 0; m < 4; ++m) a[nxt][m] = *(const short8*)(aptr[m] + ko);
#pragma unroll
            for (int nf = 0; nf < 2; ++nf)
#pragma unroll
                for (int h = 0; h < 2; ++h)
                    bf[nxt][nf][h] = *(const f32x4*)(bptr[nf] + ko + h * 4);
        }
        short8 bb[2];
#pragma unroll
        for (int nf = 0; nf < 2; ++nf) {
            union { short8 s8; ushort u[8]; } u8;
#pragma unroll
            for (int h = 0; h < 2; ++h)
#pragma unroll
                for (int j = 0; j < 4; ++j) {
                    float x = bf[cur][nf][h][j];
                    bsq[nf] = fmaf(x, x, bsq[nf]);
                    u8.u[h * 4 + j] = (ushort)(__float_as_uint(x) >> 16);
                }
            bb[nf] = u8.s8;
        }
#pragma unroll
        for (int m = 0; m < 4; ++m)
#pragma unroll
            for (int nf = 0; nf < 2; ++nf)
                acc[m][nf] = __builtin_amdgcn_mfma_f32_16x16x32_bf16(
                    a[cur][m], bb[nf], acc[m][nf], 0, 0, 0);
    }

    // finish row norms: reduce over lane-groups (lanes differing in lg)
#pragma unroll
    for (int nf = 0; nf < 2; ++nf) {
        bsq[nf] += __shfl_xor(bsq[nf], 16, 64);
        bsq[nf] += __shfl_xor(bsq[nf], 32, 64);
    }
    float rk[2] = {rsqrtf(bsq[0]), rsqrtf(bsq[1])};

    // C layout (verified): col = lane&15, row = (lane>>4)*4 + reg
#pragma unroll
    for (int m = 0; m < 4; ++m)
#pragma unroll
        for (int nf = 0; nf < 2; ++nf)
#pragma unroll
            for (int r = 0; r < 4; ++r)
                S[m * 16 + lg * 4 + r][w * WN + nf * 16 + li] = acc[m][nf][r] * rk[nf];
    __syncthreads();

    // per-block top-8 per query (thread t = query t scans 128 cols)
    if (t < BQ) {
        float v8[M_PART]; int i8[M_PART];
#pragma unroll
        for (int m = 0; m < M_PART; ++m) { v8[m] = -FLT_MAX; i8[m] = INT_MAX; }
        for (int j = 0; j < BN; ++j) {
            int n = n0 + j;
            if (n >= NK) break;
            float v = S[t][j];
            if (v > v8[M_PART - 1]) {
                int p = M_PART - 1;
                while (p > 0 && v > v8[p - 1]) {
                    v8[p] = v8[p - 1]; i8[p] = i8[p - 1]; --p;
                }
                v8[p] = v; i8[p] = n;
            }
        }
        int base = (blockIdx.x * BQ + t) * M_PART;
#pragma unroll
        for (int m = 0; m < M_PART; ++m) { pv[base + m] = v8[m]; pi[base + m] = i8[m]; }
    }
}

// ---------- phase 2+3: merge -> top-16 -> exact f32 rescore -> top-5 -> gather ----------
__device__ __forceinline__ void ins16(float v, int n, float* v16, int* i16) {
    if (v > v16[T_CAND - 1]) {
        int p = T_CAND - 1;
        while (p > 0 && v > v16[p - 1]) {
            v16[p] = v16[p - 1]; i16[p] = i16[p - 1]; --p;
        }
        v16[p] = v; i16[p] = n;
    }
}

__global__ __launch_bounds__(256) void reduce_rescore_kernel(
    const float* __restrict__ pv, const int* __restrict__ pi,
    const float* __restrict__ q, const float* __restrict__ ke,
    const int* __restrict__ kf, const float* __restrict__ qn,
    float* __restrict__ out) {
    const int qi = blockIdx.x, t = threadIdx.x;
    __shared__ float sv[256][T_CAND];
    __shared__ int   si[256][T_CAND];
    __shared__ int   ci[T_CAND];
    __shared__ float cs[T_CAND];
    __shared__ int   fi[K_TOP];

    float v16[T_CAND]; int i16[T_CAND];
#pragma unroll
    for (int m = 0; m < T_CAND; ++m) { v16[m] = -FLT_MAX; i16[m] = INT_MAX; }

    // scan this query's partials (NB1 * 8 entries)
    for (int b = t; b < NB1; b += 256) {
        int base = (b * BQ + qi) * M_PART;
#pragma unroll
        for (int m = 0; m < M_PART; ++m) ins16(pv[base + m], pi[base + m], v16, i16);
    }
#pragma unroll
    for (int m = 0; m < T_CAND; ++m) { sv[t][m] = v16[m]; si[t][m] = i16[m]; }
    __syncthreads();

    // tree merge 256 -> 64 -> 16 -> 4 -> 1 (4:1 per level)
    for (int active = 64; active >= 1; active >>= 2) {
        if (t < active) {
#pragma unroll
            for (int m = 0; m < T_CAND; ++m) { v16[m] = -FLT_MAX; i16[m] = INT_MAX; }
            for (int s = 0; s < 4; ++s) {
                int row = t * 4 + s;
#pragma unroll
                for (int m = 0; m < T_CAND; ++m) ins16(sv[row][m], si[row][m], v16, i16);
            }
        }
        __syncthreads();
        if (t < active) {
#pragma unroll
            for (int m = 0; m < T_CAND; ++m) { sv[t][m] = v16[m]; si[t][m] = i16[m]; }
        }
        __syncthreads();
    }
    if (t < T_CAND) ci[t] = si[0][t];
    __syncthreads();

    // exact f32 rescore of 16 candidates; wave w handles candidates w*4..w*4+3
    {
        const int w = t >> 6, lane = t & 63;
        for (int cc = 0; cc < 4; ++cc) {
            int c = w * 4 + cc;
            int row = ci[c];
            const float* kp = ke + (size_t)row * DD + lane * 12;
            const float* qp = q + qi * DD + lane * 12;
            float d = 0.f, ks = 0.f;
#pragma unroll
            for (int i = 0; i < 12; ++i) {
                float kv = kp[i];
                d = fmaf(qp[i], kv, d);
                ks = fmaf(kv, kv, ks);
            }
#pragma unroll
            for (int off = 32; off > 0; off >>= 1) {
                d += __shfl_xor(d, off, 64);
                ks += __shfl_xor(ks, off, 64);
            }
            if (lane == 0)
                cs[c] = d / fmaxf(qn[qi] * sqrtf(ks), 1e-8f);
        }
    }
    __syncthreads();

    // final top-5 of 16 (tie -> lower index), thread 0
    if (t == 0) {
        float v5[K_TOP]; int i5[K_TOP];
#pragma unroll
        for (int m = 0; m < K_TOP; ++m) { v5[m] = -FLT_MAX; i5[m] = INT_MAX; }
        for (int c = 0; c < T_CAND; ++c) {
            float v = cs[c]; int n = ci[c];
            if (v > v5[K_TOP - 1] || (v == v5[K_TOP - 1] && n < i5[K_TOP - 1])) {
                int p = K_TOP - 1;
                while (p > 0 && (v > v5[p - 1] || (v == v5[p - 1] && n < i5[p - 1]))) {
                    v5[p] = v5[p - 1]; i5[p] = i5[p - 1]; --p;
                }
                v5[p] = v; i5[p] = n;
            }
        }
#pragma unroll
        for (int m = 0; m < K_TOP; ++m) fi[m] = i5[m];
    }
    __syncthreads();

    // gather knowledge_full rows (ints < 30000 exact in f32)
    for (int pos = t; pos < K_TOP * LK; pos += 256) {
        int m = pos >> 5, lgi = pos & 31;
        out[(qi * K_TOP + m) * LK + lgi] = (float)kf[(size_t)fi[m] * LK + lgi];
    }
    // gather embed rows
    const int EO = BQ * K_TOP * LK;  // 10240
    for (int m = 0; m < K_TOP; ++m) {
        const float4* src = (const float4*)(ke + (size_t)fi[m] * DD);
        float4* dst = (float4*)(out + EO + (size_t)(qi * K_TOP + m) * DD);
        for (int pos = t; pos < DD / 4; pos += 256) dst[pos] = src[pos];
    }
}

extern "C" void kernel_launch(void* const* d_in, const int* in_sizes, int n_in,
                              void* d_out, int out_size, void* d_ws, size_t ws_size,
                              hipStream_t stream) {
    const float* query = (const float*)d_in[0];
    const float* ke    = (const float*)d_in[1];
    const int*   kf    = (const int*)d_in[2];
    float* out  = (float*)d_out;
    float* ws_f = (float*)d_ws;

    // ws layout (floats): pv[NB1*64*8] | pi[NB1*64*8] | qn[64] | qbf[64*768 ushort]
    const size_t NP = (size_t)NB1 * BQ * M_PART;       // 400384
    float*  pv  = ws_f;
    int*    pi  = (int*)(ws_f + NP);
    float*  qn  = ws_f + 2 * NP;
    ushort* qbf = (ushort*)(ws_f + 2 * NP + 64);       // 16B-aligned

    prep_kernel<<<BQ, 256, 0, stream>>>(query, qbf, qn);
    sims_kernel<<<NB1, 256, 0, stream>>>(qbf, ke, pv, pi);
    reduce_rescore_kernel<<<BQ, 256, 0, stream>>>(pv, pi, query, ke, kf, qn, out);
}

// Round 3
// 221.382 us; speedup vs baseline: 1.5123x; 1.5123x over previous
//
#include <hip/hip_runtime.h>
#include <cfloat>
#include <climits>

// Retriever: cosine-sim top-5 over 100k knowledge vectors + gather.
// bf16-MFMA screen (ke read f32 once, packed to bf16 in-reg via v_perm)
// -> per-block top-5 -> static-cascade merge to top-16 -> exact f32 rescore
// -> top-5 -> gather.

#define BQ 64
#define DD 768
#define NK 100000
#define LK 32
#define K_TOP 5
#define BN 64                       // n rows per block
#define NB ((NK + BN - 1) / BN)     // 1563
#define M_PART 5                    // per-block top-M partials
#define T_CAND 16                   // rescore candidate count

typedef __attribute__((ext_vector_type(8))) short short8;
typedef __attribute__((ext_vector_type(4))) float f32x4;

// ---------- phase 0: query -> bf16 (trunc) + exact f32 norms ----------
__global__ __launch_bounds__(256) void prep_kernel(const float* __restrict__ q,
                                                   ushort* __restrict__ qbf,
                                                   float* __restrict__ qn) {
    int b = blockIdx.x, t = threadIdx.x;
    float s = 0.f;
    for (int k = t; k < DD; k += 256) {
        float v = q[b * DD + k];
        s += v * v;
        qbf[b * DD + k] = (ushort)(__float_as_uint(v) >> 16);
    }
    for (int off = 32; off > 0; off >>= 1) s += __shfl_down(s, off, 64);
    __shared__ float red[4];
    if ((t & 63) == 0) red[t >> 6] = s;
    __syncthreads();
    if (t == 0) qn[b] = sqrtf(red[0] + red[1] + red[2] + red[3]);
}

// ---------- phase 1: bf16 MFMA screening ----------
// 1563 blocks x 4 waves; block tile 64q x 64n; wave tile 32q x 32n.
// Depth-3 register ring: loads for k-step kt+2 issued while computing kt.
__global__ __launch_bounds__(256) void sims_kernel(const ushort* __restrict__ qbf,
                                                   const float* __restrict__ ke,
                                                   float2* __restrict__ pvi) {
    __shared__ float S[BQ][BN + 2];

    const int t = threadIdx.x;
    const int w = t >> 6, l = t & 63;
    const int lg = l >> 4, li = l & 15;
    const int wq = w >> 1, wn = w & 1;
    const int n0 = blockIdx.x * BN;

    const ushort* aptr[2];
#pragma unroll
    for (int m = 0; m < 2; ++m)
        aptr[m] = qbf + (wq * 32 + m * 16 + li) * DD + lg * 8;
    const float* bptr[2];
#pragma unroll
    for (int nf = 0; nf < 2; ++nf) {
        int r = n0 + wn * 32 + nf * 16 + li;
        if (r >= NK) r = NK - 1;               // clamp; excluded at scan
        bptr[nf] = ke + (size_t)r * DD + lg * 8;
    }

    f32x4 acc[2][2];
#pragma unroll
    for (int m = 0; m < 2; ++m)
#pragma unroll
        for (int nf = 0; nf < 2; ++nf) acc[m][nf] = (f32x4){0.f, 0.f, 0.f, 0.f};
    float bsq[2] = {0.f, 0.f};

    short8 a_r[3][2];
    f32x4  b_r[3][2][2];

#define LOAD_STEP(slot, step) do {                                         \
        const int ko_ = (step) * 32;                                       \
        _Pragma("unroll")                                                  \
        for (int m_ = 0; m_ < 2; ++m_)                                     \
            a_r[slot][m_] = *(const short8*)(aptr[m_] + ko_);              \
        _Pragma("unroll")                                                  \
        for (int nf_ = 0; nf_ < 2; ++nf_) {                                \
            b_r[slot][nf_][0] = *(const f32x4*)(bptr[nf_] + ko_);          \
            b_r[slot][nf_][1] = *(const f32x4*)(bptr[nf_] + ko_ + 4);      \
        }                                                                  \
    } while (0)

    LOAD_STEP(0, 0);
    LOAD_STEP(1, 1);

#pragma unroll
    for (int kt = 0; kt < 24; ++kt) {
        const int cs = kt % 3;
        if (kt < 22) LOAD_STEP((kt + 2) % 3, kt + 2);

        short8 bb[2];
#pragma unroll
        for (int nf = 0; nf < 2; ++nf) {
            union { short8 s8; uint u[4]; } pk;
#pragma unroll
            for (int p = 0; p < 4; ++p) {
                float f0 = b_r[cs][nf][p >> 1][(p & 1) * 2 + 0];
                float f1 = b_r[cs][nf][p >> 1][(p & 1) * 2 + 1];
                bsq[nf] = fmaf(f0, f0, bsq[nf]);
                bsq[nf] = fmaf(f1, f1, bsq[nf]);
                pk.u[p] = __builtin_amdgcn_perm(__float_as_uint(f1),
                                                __float_as_uint(f0), 0x07060302u);
            }
            bb[nf] = pk.s8;
        }
#pragma unroll
        for (int m = 0; m < 2; ++m)
#pragma unroll
            for (int nf = 0; nf < 2; ++nf)
                acc[m][nf] = __builtin_amdgcn_mfma_f32_16x16x32_bf16(
                    a_r[cs][m], bb[nf], acc[m][nf], 0, 0, 0);
    }
#undef LOAD_STEP

    // row-norm finish: sum over the 4 lg groups (lanes same li)
#pragma unroll
    for (int nf = 0; nf < 2; ++nf) {
        bsq[nf] += __shfl_xor(bsq[nf], 16, 64);
        bsq[nf] += __shfl_xor(bsq[nf], 32, 64);
    }
    float rk[2] = {rsqrtf(bsq[0]), rsqrtf(bsq[1])};

    // C layout (HW-verified r1): col(n)=lane&15, row(q)=(lane>>4)*4+reg
#pragma unroll
    for (int m = 0; m < 2; ++m)
#pragma unroll
        for (int nf = 0; nf < 2; ++nf)
#pragma unroll
            for (int r = 0; r < 4; ++r)
                S[wq * 32 + m * 16 + lg * 4 + r][wn * 32 + nf * 16 + li] =
                    acc[m][nf][r] * rk[nf];
    __syncthreads();

    // per-block top-5 per query, static compare-swap cascade (regs only)
    if (t < BQ) {
        float v5[M_PART]; int i5[M_PART];
#pragma unroll
        for (int m = 0; m < M_PART; ++m) { v5[m] = -FLT_MAX; i5[m] = INT_MAX; }
        for (int j = 0; j < BN; ++j) {
            int n = n0 + j;
            if (n >= NK) break;
            float v = S[t][j];
#pragma unroll
            for (int m = 0; m < M_PART; ++m) {
                if (v > v5[m]) {
                    float tv = v5[m]; v5[m] = v; v = tv;
                    int ti = i5[m]; i5[m] = n; n = ti;
                }
            }
        }
        float2* dst = pvi + ((size_t)t * NB + blockIdx.x) * M_PART;
#pragma unroll
        for (int m = 0; m < M_PART; ++m)
            dst[m] = make_float2(v5[m], __int_as_float(i5[m]));
    }
}

// ---------- phase 2+3: merge -> top-16 -> exact f32 rescore -> top-5 -> gather ----------
#define INS8(v, n, va, ia)                                                  \
    _Pragma("unroll")                                                       \
    for (int m_ = 0; m_ < 8; ++m_) {                                        \
        if ((v) > va[m_]) {                                                 \
            float tv_ = va[m_]; va[m_] = (v); (v) = tv_;                    \
            int ti_ = ia[m_]; ia[m_] = (n); (n) = ti_;                      \
        }                                                                   \
    }

__global__ __launch_bounds__(256) void reduce_rescore_kernel(
    const float2* __restrict__ pvi,
    const float* __restrict__ q, const float* __restrict__ ke,
    const int* __restrict__ kf, const float* __restrict__ qn,
    float* __restrict__ out) {
    const int qi = blockIdx.x, t = threadIdx.x;
    __shared__ float sv[256][8];
    __shared__ int   si[256][8];
    __shared__ int   ci[T_CAND];
    __shared__ float cs_[T_CAND];
    __shared__ int   fi[K_TOP];

    float v8[8]; int i8[8];
#pragma unroll
    for (int m = 0; m < 8; ++m) { v8[m] = -FLT_MAX; i8[m] = INT_MAX; }

    // coalesced scan of this query's partials [NB*5]
    const float2* src = pvi + (size_t)qi * NB * M_PART;
    const int NCand = NB * M_PART;   // 7815
    for (int c = t; c < NCand; c += 256) {
        float2 e = src[c];
        float v = e.x; int n = __float_as_int(e.y);
        INS8(v, n, v8, i8);
    }
#pragma unroll
    for (int m = 0; m < 8; ++m) { sv[t][m] = v8[m]; si[t][m] = i8[m]; }
    __syncthreads();

    // tree merge 256 -> 64 -> 16 -> 4 rows (top-8 each), all static-indexed
    for (int active = 64; active >= 4; active >>= 2) {
        if (t < active) {
#pragma unroll
            for (int m = 0; m < 8; ++m) { v8[m] = -FLT_MAX; i8[m] = INT_MAX; }
            for (int s = 0; s < 4; ++s) {
                int row = t * 4 + s;
#pragma unroll
                for (int m = 0; m < 8; ++m) {
                    float v = sv[row][m]; int n = si[row][m];
                    INS8(v, n, v8, i8);
                }
            }
        }
        __syncthreads();
        if (t < active) {
#pragma unroll
            for (int m = 0; m < 8; ++m) { sv[t][m] = v8[m]; si[t][m] = i8[m]; }
        }
        __syncthreads();
    }

    // thread 0: 4 rows x 8 -> top-16
    if (t == 0) {
        float v16[T_CAND]; int i16[T_CAND];
#pragma unroll
        for (int m = 0; m < T_CAND; ++m) { v16[m] = -FLT_MAX; i16[m] = INT_MAX; }
        for (int row = 0; row < 4; ++row) {
#pragma unroll
            for (int m = 0; m < 8; ++m) {
                float v = sv[row][m]; int n = si[row][m];
#pragma unroll
                for (int p = 0; p < T_CAND; ++p) {
                    if (v > v16[p]) {
                        float tv = v16[p]; v16[p] = v; v = tv;
                        int ti = i16[p]; i16[p] = n; n = ti;
                    }
                }
            }
        }
#pragma unroll
        for (int m = 0; m < T_CAND; ++m) ci[m] = i16[m];
    }
    __syncthreads();

    // exact f32 rescore; wave w -> candidates w*4..w*4+3
    {
        const int w = t >> 6, lane = t & 63;
        for (int cc = 0; cc < 4; ++cc) {
            int c = w * 4 + cc;
            int row = ci[c];
            const float* kp = ke + (size_t)row * DD + lane * 12;
            const float* qp = q + qi * DD + lane * 12;
            float d = 0.f, ks = 0.f;
#pragma unroll
            for (int i = 0; i < 12; ++i) {
                float kv = kp[i];
                d = fmaf(qp[i], kv, d);
                ks = fmaf(kv, kv, ks);
            }
#pragma unroll
            for (int off = 32; off > 0; off >>= 1) {
                d += __shfl_xor(d, off, 64);
                ks += __shfl_xor(ks, off, 64);
            }
            if (lane == 0)
                cs_[c] = d / fmaxf(qn[qi] * sqrtf(ks), 1e-8f);
        }
    }
    __syncthreads();

    // final top-5 of 16 (tie -> lower index), static cascade
    if (t == 0) {
        float v5[K_TOP]; int i5[K_TOP];
#pragma unroll
        for (int m = 0; m < K_TOP; ++m) { v5[m] = -FLT_MAX; i5[m] = INT_MAX; }
        for (int c = 0; c < T_CAND; ++c) {
            float v = cs_[c]; int n = ci[c];
#pragma unroll
            for (int m = 0; m < K_TOP; ++m) {
                bool take = (v > v5[m]) || (v == v5[m] && n < i5[m]);
                if (take) {
                    float tv = v5[m]; v5[m] = v; v = tv;
                    int ti = i5[m]; i5[m] = n; n = ti;
                }
            }
        }
#pragma unroll
        for (int m = 0; m < K_TOP; ++m) fi[m] = i5[m];
    }
    __syncthreads();

    // gather knowledge_full rows (ints < 30000 exact in f32)
    for (int pos = t; pos < K_TOP * LK; pos += 256) {
        int m = pos >> 5, lgi = pos & 31;
        out[(qi * K_TOP + m) * LK + lgi] = (float)kf[(size_t)fi[m] * LK + lgi];
    }
    // gather embed rows
    const int EO = BQ * K_TOP * LK;  // 10240
    for (int m = 0; m < K_TOP; ++m) {
        const float4* srcp = (const float4*)(ke + (size_t)fi[m] * DD);
        float4* dstp = (float4*)(out + EO + (size_t)(qi * K_TOP + m) * DD);
        for (int pos = t; pos < DD / 4; pos += 256) dstp[pos] = srcp[pos];
    }
}

extern "C" void kernel_launch(void* const* d_in, const int* in_sizes, int n_in,
                              void* d_out, int out_size, void* d_ws, size_t ws_size,
                              hipStream_t stream) {
    const float* query = (const float*)d_in[0];
    const float* ke    = (const float*)d_in[1];
    const int*   kf    = (const int*)d_in[2];
    float* out = (float*)d_out;

    // ws layout: pvi [64][NB][5] float2 (4.0 MB) | qn[64] f32 | qbf[64*768] ushort
    float2* pvi = (float2*)d_ws;
    float*  qn  = (float*)((char*)d_ws + (size_t)BQ * NB * M_PART * sizeof(float2));
    ushort* qbf = (ushort*)(qn + 64);

    prep_kernel<<<BQ, 256, 0, stream>>>(query, qbf, qn);
    sims_kernel<<<NB, 256, 0, stream>>>(qbf, ke, pvi);
    reduce_rescore_kernel<<<BQ, 256, 0, stream>>>(pvi, query, ke, kf, qn, out);
}